// Round 5
// baseline (355.616 us; speedup 1.0000x reference)
//
#include <hip/hip_runtime.h>
#include <math.h>

// ---------------------------------------------------------------------------
// 3-layer GCN, CSR-gather formulation.
// Round 18: revert the R17 shfl-broadcast gather (measured 2.1x REGRESSION:
// 44.8 -> 94.5 us; the coalesced-esrc + ds_bpermute chain serialized the
// per-node critical path). Direct per-quad indexed gather restored (44.8 us,
// at the XCD compulsory-miss floor). KEEP the zgemm fusion (deletes k_zgemm
// + 25.6 MB a2s round-trip). NEW: ebuf packed int ((d&511)<<17 | s) halves
// bscatter write / csr read traffic.  Requires N <= 131072.
// N=100000, E=1200000, F: 128 -> 64 -> 64 -> 40
// ---------------------------------------------------------------------------

static inline int cdiv(long a, int b) { return (int)((a + b - 1) / b); }

// ---- bf16 helpers (RNE) ----
__device__ __forceinline__ unsigned short f2bf(float f) {
    unsigned u = __float_as_uint(f);
    u += 0x7fffu + ((u >> 16) & 1u);
    return (unsigned short)(u >> 16);
}
__device__ __forceinline__ float bf2f(unsigned short b) {
    return __uint_as_float(((unsigned)b) << 16);
}

// ---- radix-bucket CSR build ----
#define RSH 9
#define RNODES 512            // 1 << RSH nodes per bucket
#define GB 256                // blocks in bucket-hist / bucket-scatter passes
#define NBMAX 256             // max buckets (N <= 131072)
#define SMASK 0x1FFFF         // 17-bit src mask (N <= 131072)

// K1: per-block bucket histogram (LDS atomics only).
__global__ __launch_bounds__(256)
void k_bhist(const int* __restrict__ dst, int* __restrict__ bh,
             int E, int NB, int EPB) {
    __shared__ int bcnt[NBMAX];
    const int tid = threadIdx.x, blk = blockIdx.x;
    for (int i = tid; i < NB; i += 256) bcnt[i] = 0;
    __syncthreads();
    const int e1 = min(E, (blk + 1) * EPB);
    for (int e = blk * EPB + tid; e < e1; e += 256)
        atomicAdd(&bcnt[dst[e] >> RSH], 1);
    __syncthreads();
    for (int i = tid; i < NB; i += 256) bh[i * GB + blk] = bcnt[i];
}

// K2: scatter edges into bucket-grouped ebuf (LDS cursors, no global atomics).
// Packed entry: (dst & 511) << 17 | src.
__global__ __launch_bounds__(256)
void k_bscatter(const int* __restrict__ src, const int* __restrict__ dst,
                const int* __restrict__ eoff, int* __restrict__ ebuf,
                int E, int NB, int EPB) {
    __shared__ int cur[NBMAX];
    const int tid = threadIdx.x, blk = blockIdx.x;
    for (int i = tid; i < NB; i += 256) cur[i] = eoff[i * GB + blk];
    __syncthreads();
    const int e1 = min(E, (blk + 1) * EPB);
    for (int e = blk * EPB + tid; e < e1; e += 256) {
        int d = dst[e];
        int s = src[e];
        int pos = atomicAdd(&cur[d >> RSH], 1);
        ebuf[pos] = ((d & (RNODES - 1)) << 17) | s;
    }
}

// K3: per-bucket CSR finalize (LDS hist + scan + rank-scatter).
__global__ __launch_bounds__(1024)
void k_csr(const int* __restrict__ ebuf, const int* __restrict__ eoff,
           int* __restrict__ rp, float* __restrict__ dis, int* __restrict__ esrc,
           int N, int E, int NB) {
    __shared__ int cnt[RNODES];
    __shared__ int cur[RNODES];
    __shared__ int sm[1024];
    const int tid = threadIdx.x, b = blockIdx.x;
    const int node0 = b << RSH;
    const int bb = eoff[b * GB];
    const int be = (b + 1 == NB) ? E : eoff[(b + 1) * GB];

    if (tid < RNODES) cnt[tid] = 0;
    __syncthreads();
    for (int e = bb + tid; e < be; e += 1024)
        atomicAdd(&cnt[ebuf[e] >> 17], 1);
    __syncthreads();

    int v = (tid < RNODES) ? cnt[tid] : 0;
    sm[tid] = v;
    __syncthreads();
    for (int off = 1; off < RNODES; off <<= 1) {
        int t = (tid >= off) ? sm[tid - off] : 0;
        __syncthreads();
        sm[tid] += t;
        __syncthreads();
    }
    if (tid < RNODES) {
        int excl = sm[tid] - v;
        cur[tid] = excl;
        int node = node0 + tid;
        if (node < N) {
            rp[node] = bb + excl;
            dis[node] = rsqrtf(1.0f + (float)v);   // +1 self-loop
        }
    }
    if (b == 0 && tid == 0) rp[N] = E;
    __syncthreads();

    for (int e = bb + tid; e < be; e += 1024) {
        int ev = ebuf[e];
        int slot = atomicAdd(&cur[ev >> 17], 1);
        esrc[bb + slot] = ev & SMASK;
    }
}

// ---- 3-step exclusive scan (for the [bucket][block] matrix) ----
#define SCAN_B 1024
__global__ void k_scan1(const int* __restrict__ cnt, int* __restrict__ rp,
                        int* __restrict__ bsum, int n) {
    __shared__ int sm[SCAN_B];
    const int tid = threadIdx.x;
    const int gid = blockIdx.x * SCAN_B + tid;
    int v = (gid < n) ? cnt[gid] : 0;
    sm[tid] = v;
    __syncthreads();
    for (int off = 1; off < SCAN_B; off <<= 1) {
        int t = (tid >= off) ? sm[tid - off] : 0;
        __syncthreads();
        sm[tid] += t;
        __syncthreads();
    }
    if (gid < n) rp[gid] = sm[tid] - v;           // exclusive
    if (tid == SCAN_B - 1) bsum[blockIdx.x] = sm[tid];
}

__global__ void k_scan2(int* __restrict__ bsum, int nb) {
    __shared__ int sm[SCAN_B];
    const int tid = threadIdx.x;
    int v = (tid < nb) ? bsum[tid] : 0;
    sm[tid] = v;
    __syncthreads();
    for (int off = 1; off < SCAN_B; off <<= 1) {
        int t = (tid >= off) ? sm[tid - off] : 0;
        __syncthreads();
        sm[tid] += t;
        __syncthreads();
    }
    if (tid < nb) bsum[tid] = sm[tid] - v;        // exclusive
}

__global__ void k_scan3(int* __restrict__ rp, const int* __restrict__ bsum, int n, int E) {
    const int gid = blockIdx.x * SCAN_B + threadIdx.x;
    if (gid < n) rp[gid] += bsum[gid / SCAN_B];
    if (gid == n) rp[n] = E;
}

__device__ __forceinline__ void fma4(float a, const float4& w, float4& acc) {
    acc.x = fmaf(a, w.x, acc.x);
    acc.y = fmaf(a, w.y, acc.y);
    acc.z = fmaf(a, w.z, acc.z);
    acc.w = fmaf(a, w.w, acc.w);
}

// LDS-tiled GEMM with fused dis-scale: Hs[N,64] = (X[N,K] @ W[K,64]) * dis[row].
template<int K, bool BF16OUT>
__global__ __launch_bounds__(256, 2)
void k_gemm_lds(const float* __restrict__ X, const float* __restrict__ W,
                const float* __restrict__ dis, void* __restrict__ Hout, int N) {
    constexpr int KP = K + 4;                 // padded X row stride (floats)
    __shared__ float xs[64 * KP];
    __shared__ float wsh[K * 64];
    const int tid = threadIdx.x;
    const int tx = tid & 15;                  // col group (4 cols)
    const int ty = tid >> 4;                  // row group (4 rows)
    const int row0 = blockIdx.x * 64;

    {
        const float4* Wg = (const float4*)W;
        float4* Wl = (float4*)wsh;
#pragma unroll
        for (int i = 0; i < K * 16 / 256; ++i)
            Wl[i * 256 + tid] = Wg[i * 256 + tid];
    }
    {
        constexpr int F4 = K / 4;             // float4 per row
        for (int i = tid; i < 64 * F4; i += 256) {
            int r = i / F4, c = i - r * F4;
            int gr = min(row0 + r, N - 1);
            float4 v = *(const float4*)(X + (size_t)gr * K + c * 4);
            *(float4*)(xs + r * KP + c * 4) = v;
        }
    }
    __syncthreads();

    float4 acc0 = {0.f, 0.f, 0.f, 0.f};
    float4 acc1 = {0.f, 0.f, 0.f, 0.f};
    float4 acc2 = {0.f, 0.f, 0.f, 0.f};
    float4 acc3 = {0.f, 0.f, 0.f, 0.f};

    const float* xr0 = xs + (ty * 4 + 0) * KP;
    const float* xr1 = xs + (ty * 4 + 1) * KP;
    const float* xr2 = xs + (ty * 4 + 2) * KP;
    const float* xr3 = xs + (ty * 4 + 3) * KP;

#pragma unroll 2
    for (int k = 0; k < K; k += 4) {
        float4 w0 = *(const float4*)(wsh + (k + 0) * 64 + tx * 4);
        float4 w1 = *(const float4*)(wsh + (k + 1) * 64 + tx * 4);
        float4 w2 = *(const float4*)(wsh + (k + 2) * 64 + tx * 4);
        float4 w3 = *(const float4*)(wsh + (k + 3) * 64 + tx * 4);
        float4 xa = *(const float4*)(xr0 + k);
        float4 xb = *(const float4*)(xr1 + k);
        float4 xc = *(const float4*)(xr2 + k);
        float4 xd = *(const float4*)(xr3 + k);

        fma4(xa.x, w0, acc0); fma4(xa.y, w1, acc0); fma4(xa.z, w2, acc0); fma4(xa.w, w3, acc0);
        fma4(xb.x, w0, acc1); fma4(xb.y, w1, acc1); fma4(xb.z, w2, acc1); fma4(xb.w, w3, acc1);
        fma4(xc.x, w0, acc2); fma4(xc.y, w1, acc2); fma4(xc.z, w2, acc2); fma4(xc.w, w3, acc2);
        fma4(xd.x, w0, acc3); fma4(xd.y, w1, acc3); fma4(xd.z, w2, acc3); fma4(xd.w, w3, acc3);
    }

    const int r = row0 + ty * 4;
#pragma unroll
    for (int i = 0; i < 4; ++i) {
        if (r + i >= N) break;
        float4 a = (i == 0) ? acc0 : (i == 1) ? acc1 : (i == 2) ? acc2 : acc3;
        float d = dis[r + i];
        a.x *= d; a.y *= d; a.z *= d; a.w *= d;
        if (BF16OUT) {
            ushort4 o;
            o.x = f2bf(a.x); o.y = f2bf(a.y); o.z = f2bf(a.z); o.w = f2bf(a.w);
            *(ushort4*)((unsigned short*)Hout + (size_t)(r + i) * 64 + tx * 4) = o;
        } else {
            *(float4*)((float*)Hout + (size_t)(r + i) * 64 + tx * 4) = a;
        }
    }
}

// Wave-per-node segmented row-sum, quad-per-edge, bf16 gather rows (128 B).
// Direct-indexed 2-deep gather (R1 structure, measured 44.8 us — at the
// compulsory-miss floor; shfl-broadcast variant measured 94.5 us, reverted).
// MODE 0: A = relu(t + bias)                   -> fp32  (layer 1, GEMM input)
// MODE 1: z = bf16( (relu(t+bias)*dis) @ W3 )  -> bf16 N x 40 (fused zgemm)
template<int MODE>
__global__ __launch_bounds__(256, 8)
void k_agg(const unsigned short* __restrict__ Hs, const float* __restrict__ dis,
           const int* __restrict__ rp, const int* __restrict__ esrc,
           const float* __restrict__ bias, const float* __restrict__ W3,
           void* __restrict__ A, int N) {
    __shared__ float a2[4][64];
    const int wave = threadIdx.x >> 6;
    const int lane = threadIdx.x & 63;
    int node = blockIdx.x * 4 + wave;
    if (node >= N) node = N - 1;       // clamp: dup wave redoes node N-1 (benign)
    const int q  = lane >> 4;          // quad 0..3 -> interleaved edges
    const int f4 = lane & 15;          // 4-feature group within the 64-f row

    const int e0 = rp[node];
    const int e1 = rp[node + 1];

    // hoist self-row + scalars (overlap with gather)
    const float dd = dis[node];
    ushort4 sh = *(const ushort4*)(Hs + (size_t)node * 64 + f4 * 4);
    float4 bv = ((const float4*)bias)[f4];

    float4 acc = {0.f, 0.f, 0.f, 0.f};
    int e = e0 + q;
    for (; e + 4 < e1; e += 8) {       // 2 edges per quad per round
        int s0 = esrc[e];
        int s1 = esrc[e + 4];
        ushort4 h0 = *(const ushort4*)(Hs + (size_t)s0 * 64 + f4 * 4);
        ushort4 h1 = *(const ushort4*)(Hs + (size_t)s1 * 64 + f4 * 4);
        acc.x += bf2f(h0.x) + bf2f(h1.x);
        acc.y += bf2f(h0.y) + bf2f(h1.y);
        acc.z += bf2f(h0.z) + bf2f(h1.z);
        acc.w += bf2f(h0.w) + bf2f(h1.w);
    }
    for (; e < e1; e += 4) {
        int s = esrc[e];
        ushort4 h = *(const ushort4*)(Hs + (size_t)s * 64 + f4 * 4);
        acc.x += bf2f(h.x); acc.y += bf2f(h.y); acc.z += bf2f(h.z); acc.w += bf2f(h.w);
    }
    // cross-quad reduce (after: lanes 0..15 hold the full row sum)
    acc.x += __shfl_xor(acc.x, 16, 64);
    acc.y += __shfl_xor(acc.y, 16, 64);
    acc.z += __shfl_xor(acc.z, 16, 64);
    acc.w += __shfl_xor(acc.w, 16, 64);
    acc.x += __shfl_xor(acc.x, 32, 64);
    acc.y += __shfl_xor(acc.y, 32, 64);
    acc.z += __shfl_xor(acc.z, 32, 64);
    acc.w += __shfl_xor(acc.w, 32, 64);

    float4 v;
    if (lane < 16) {
        v.x = fmaxf((acc.x + bf2f(sh.x)) * dd + bv.x, 0.f);
        v.y = fmaxf((acc.y + bf2f(sh.y)) * dd + bv.y, 0.f);
        v.z = fmaxf((acc.z + bf2f(sh.z)) * dd + bv.z, 0.f);
        v.w = fmaxf((acc.w + bf2f(sh.w)) * dd + bv.w, 0.f);
    }

    if (MODE == 0) {
        if (lane < 16)
            *(float4*)((float*)A + (size_t)node * 64 + lane * 4) = v;
    } else {
        // fused z = (v * dd) @ W3  (a2s kept fp32 in LDS; one bf16 round at z)
        if (lane < 16) {
            v.x *= dd; v.y *= dd; v.z *= dd; v.w *= dd;
            *(float4*)&a2[wave][lane * 4] = v;
        }
        __syncthreads();
        const int c = (lane < 40) ? lane : 0;
        float zacc = 0.f;
#pragma unroll 8
        for (int k = 0; k < 64; ++k)
            zacc = fmaf(a2[wave][k], W3[k * 40 + c], zacc);
        if (lane < 40)
            ((unsigned short*)A)[(size_t)node * 40 + lane] = f2bf(zacc);
    }
}

// Fused layer-3 gather + log_softmax over 80 B bf16 z-rows (R2 structure,
// measured 53.2 us). 6 groups x 10 lanes; lanes 60..63 idle.
__global__ __launch_bounds__(256, 8)
void k_agg40lsm(const unsigned short* __restrict__ Z, const float* __restrict__ dis,
                const int* __restrict__ rp, const int* __restrict__ esrc,
                const float* __restrict__ b3, float* __restrict__ out, int N) {
    __shared__ float4 red[4][64];
    const int wave = threadIdx.x >> 6;
    const int lane = threadIdx.x & 63;
    int node = blockIdx.x * 4 + wave;
    if (node >= N) node = N - 1;          // clamp: dup work, no barrier hazard
    const int q = lane / 10;              // 0..6 (q==6 -> idle)
    const int f = lane - q * 10;          // 0..9
    const bool act = (q < 6);

    const int e0 = rp[node];
    const int e1 = rp[node + 1];
    float4 acc = {0.f, 0.f, 0.f, 0.f};
    if (act) {
        for (int e = e0 + q; e < e1; e += 6) {
            int s = esrc[e];
            ushort4 h = *(const ushort4*)(Z + (size_t)s * 40 + f * 4);
            acc.x += bf2f(h.x); acc.y += bf2f(h.y); acc.z += bf2f(h.z); acc.w += bf2f(h.w);
        }
    }
    red[wave][lane] = acc;
    __syncthreads();

    float4 v;
    float m4 = -INFINITY;
    if (lane < 10) {
        float4 a0 = red[wave][lane];
        float4 a1 = red[wave][10 + lane];
        float4 a2 = red[wave][20 + lane];
        float4 a3 = red[wave][30 + lane];
        float4 a4 = red[wave][40 + lane];
        float4 a5 = red[wave][50 + lane];
        v.x = a0.x + a1.x + a2.x + a3.x + a4.x + a5.x;
        v.y = a0.y + a1.y + a2.y + a3.y + a4.y + a5.y;
        v.z = a0.z + a1.z + a2.z + a3.z + a4.z + a5.z;
        v.w = a0.w + a1.w + a2.w + a3.w + a4.w + a5.w;
        ushort4 sh = *(const ushort4*)(Z + (size_t)node * 40 + lane * 4);
        const float dd = dis[node];
        float4 bv = ((const float4*)b3)[lane];
        v.x = (v.x + bf2f(sh.x)) * dd + bv.x;
        v.y = (v.y + bf2f(sh.y)) * dd + bv.y;
        v.z = (v.z + bf2f(sh.z)) * dd + bv.z;
        v.w = (v.w + bf2f(sh.w)) * dd + bv.w;
        m4 = fmaxf(fmaxf(v.x, v.y), fmaxf(v.z, v.w));
    }
    float m = m4;
#pragma unroll
    for (int o = 1; o < 16; o <<= 1) m = fmaxf(m, __shfl_xor(m, o, 64));
    float es = 0.f;
    if (lane < 10) {
        es = expf(v.x - m) + expf(v.y - m) + expf(v.z - m) + expf(v.w - m);
    }
#pragma unroll
    for (int o = 1; o < 16; o <<= 1) es += __shfl_xor(es, o, 64);
    if (lane < 10) {
        float ls = logf(es);
        float4 o4;
        o4.x = v.x - m - ls;
        o4.y = v.y - m - ls;
        o4.z = v.z - m - ls;
        o4.w = v.w - m - ls;
        *(float4*)(out + (size_t)node * 40 + lane * 4) = o4;
    }
}

extern "C" void kernel_launch(void* const* d_in, const int* in_sizes, int n_in,
                              void* d_out, int out_size, void* d_ws, size_t ws_size,
                              hipStream_t stream) {
    const float* x  = (const float*)d_in[0];
    const int*   ei = (const int*)d_in[1];
    const float* W1 = (const float*)d_in[2];
    const float* b1 = (const float*)d_in[3];
    const float* W2 = (const float*)d_in[4];
    const float* b2 = (const float*)d_in[5];
    const float* W3 = (const float*)d_in[6];
    const float* b3 = (const float*)d_in[7];
    float* out = (float*)d_out;

    const int N = in_sizes[0] / 128;
    const int E = in_sizes[1] / 2;
    const int* src = ei;
    const int* dst = ei + E;

    const int NB   = cdiv(N, RNODES);        // buckets (196 @ N=100000)
    const int EPB  = cdiv(E, GB);            // edges per hist/scatter block
    const int nscan = NB * GB;               // scan length (50176)

    // ---- workspace layout ----
    // buf0: ebuf int (CSR build) -> Hs1 bf16 -> Hs2 bf16
    // buf1: a1 fp32 -> z bf16 (N x 40)
    char* ws = (char*)d_ws;
    char* buf0  = ws;                         ws += (size_t)N * 64 * sizeof(float); // 25.6 MB
    char* buf1  = ws;                         ws += (size_t)N * 64 * sizeof(float); // 25.6 MB
    int*   esrc  = (int*)ws;                  ws += (size_t)E * sizeof(int);        // 4.8 MB
    int*   rp    = (int*)ws;                  ws += (size_t)(N + 1) * sizeof(int);
    int*   bsum  = (int*)ws;                  ws += (size_t)SCAN_B * sizeof(int);
    float* dis   = (float*)ws;                ws += (size_t)N * sizeof(float);
    int*   bh    = (int*)ws;                  ws += (size_t)nscan * sizeof(int);    // 200 KB
    int*   eoff  = (int*)ws;                  ws += (size_t)(nscan + 1) * sizeof(int);
    int*   ebuf  = (int*)buf0;                // 4.8 MB, consumed before gemm1 writes buf0

    const int B = 256;
    const int nbs = cdiv(nscan, SCAN_B);

    // ---- CSR build: two-level counting sort, zero global atomics ----
    k_bhist<<<GB, B, 0, stream>>>(dst, bh, E, NB, EPB);
    k_scan1<<<nbs, SCAN_B, 0, stream>>>(bh, eoff, bsum, nscan);
    k_scan2<<<1, SCAN_B, 0, stream>>>(bsum, nbs);
    k_scan3<<<cdiv(nscan + 1, SCAN_B), SCAN_B, 0, stream>>>(eoff, bsum, nscan, E);
    k_bscatter<<<GB, B, 0, stream>>>(src, dst, eoff, ebuf, E, NB, EPB);
    k_csr<<<NB, 1024, 0, stream>>>(ebuf, eoff, rp, dis, esrc, N, E, NB);

    // ---- layer 1: Hs1 = bf16((x@W1)*dis); a1 = relu(dis*sum + b1) fp32 ----
    k_gemm_lds<128, true><<<cdiv(N, 64), B, 0, stream>>>(x, W1, dis, buf0, N);
    k_agg<0><<<cdiv(N, 4), B, 0, stream>>>((const unsigned short*)buf0, dis, rp, esrc,
                                           b1, nullptr, buf1, N);

    // ---- layer 2: Hs2 = bf16((a1@W2)*dis); z = bf16((relu(dis*sum+b2)*dis)@W3) ----
    k_gemm_lds<64, true><<<cdiv(N, 64), B, 0, stream>>>((const float*)buf1, W2, dis, buf0, N);
    k_agg<1><<<cdiv(N, 4), B, 0, stream>>>((const unsigned short*)buf0, dis, rp, esrc,
                                           b2, W3, buf1, N);

    // ---- layer 3: out = lsm(dis*(z self+sum) + b3) ----
    k_agg40lsm<<<cdiv(N, 4), B, 0, stream>>>((const unsigned short*)buf1, dis, rp, esrc,
                                             b3, out, N);
}

// Round 6
// 338.968 us; speedup vs baseline: 1.0491x; 1.0491x over previous
//
#include <hip/hip_runtime.h>
#include <math.h>

// ---------------------------------------------------------------------------
// 3-layer GCN, CSR-gather formulation.
// Round 19: UNFUSE the W3 matvec from k_agg<1> (fusion measured +50 us:
// 44.8 -> 95.5; cause = per-block __syncthreads coupling degree variance +
// 64-iter serial matvec on the node critical path — NOT the gather loop,
// which was misblamed in R17/R18). Layer 3 now: k_zgemm -> z64 table
// (N x 64 bf16, 40 valid) -> k_aggz = proven k_agg gather geometry
// (4 quads x 16 lanes x ushort4, 128 B rows) + wave-local shfl-only
// log-softmax epilogue (no LDS, no barrier). CSR build keeps packed-int
// ebuf ((d&511)<<17|s, N <= 131072).
// N=100000, E=1200000, F: 128 -> 64 -> 64 -> 40
// ---------------------------------------------------------------------------

static inline int cdiv(long a, int b) { return (int)((a + b - 1) / b); }

// ---- bf16 helpers (RNE) ----
__device__ __forceinline__ unsigned short f2bf(float f) {
    unsigned u = __float_as_uint(f);
    u += 0x7fffu + ((u >> 16) & 1u);
    return (unsigned short)(u >> 16);
}
__device__ __forceinline__ float bf2f(unsigned short b) {
    return __uint_as_float(((unsigned)b) << 16);
}

// ---- radix-bucket CSR build ----
#define RSH 9
#define RNODES 512            // 1 << RSH nodes per bucket
#define GB 256                // blocks in bucket-hist / bucket-scatter passes
#define NBMAX 256             // max buckets (N <= 131072)
#define SMASK 0x1FFFF         // 17-bit src mask (N <= 131072)

// K1: per-block bucket histogram (LDS atomics only).
__global__ __launch_bounds__(256)
void k_bhist(const int* __restrict__ dst, int* __restrict__ bh,
             int E, int NB, int EPB) {
    __shared__ int bcnt[NBMAX];
    const int tid = threadIdx.x, blk = blockIdx.x;
    for (int i = tid; i < NB; i += 256) bcnt[i] = 0;
    __syncthreads();
    const int e1 = min(E, (blk + 1) * EPB);
    for (int e = blk * EPB + tid; e < e1; e += 256)
        atomicAdd(&bcnt[dst[e] >> RSH], 1);
    __syncthreads();
    for (int i = tid; i < NB; i += 256) bh[i * GB + blk] = bcnt[i];
}

// K2: scatter edges into bucket-grouped ebuf (LDS cursors, no global atomics).
// Packed entry: (dst & 511) << 17 | src.
__global__ __launch_bounds__(256)
void k_bscatter(const int* __restrict__ src, const int* __restrict__ dst,
                const int* __restrict__ eoff, int* __restrict__ ebuf,
                int E, int NB, int EPB) {
    __shared__ int cur[NBMAX];
    const int tid = threadIdx.x, blk = blockIdx.x;
    for (int i = tid; i < NB; i += 256) cur[i] = eoff[i * GB + blk];
    __syncthreads();
    const int e1 = min(E, (blk + 1) * EPB);
    for (int e = blk * EPB + tid; e < e1; e += 256) {
        int d = dst[e];
        int s = src[e];
        int pos = atomicAdd(&cur[d >> RSH], 1);
        ebuf[pos] = ((d & (RNODES - 1)) << 17) | s;
    }
}

// K3: per-bucket CSR finalize (LDS hist + scan + rank-scatter).
__global__ __launch_bounds__(1024)
void k_csr(const int* __restrict__ ebuf, const int* __restrict__ eoff,
           int* __restrict__ rp, float* __restrict__ dis, int* __restrict__ esrc,
           int N, int E, int NB) {
    __shared__ int cnt[RNODES];
    __shared__ int cur[RNODES];
    __shared__ int sm[1024];
    const int tid = threadIdx.x, b = blockIdx.x;
    const int node0 = b << RSH;
    const int bb = eoff[b * GB];
    const int be = (b + 1 == NB) ? E : eoff[(b + 1) * GB];

    if (tid < RNODES) cnt[tid] = 0;
    __syncthreads();
    for (int e = bb + tid; e < be; e += 1024)
        atomicAdd(&cnt[ebuf[e] >> 17], 1);
    __syncthreads();

    int v = (tid < RNODES) ? cnt[tid] : 0;
    sm[tid] = v;
    __syncthreads();
    for (int off = 1; off < RNODES; off <<= 1) {
        int t = (tid >= off) ? sm[tid - off] : 0;
        __syncthreads();
        sm[tid] += t;
        __syncthreads();
    }
    if (tid < RNODES) {
        int excl = sm[tid] - v;
        cur[tid] = excl;
        int node = node0 + tid;
        if (node < N) {
            rp[node] = bb + excl;
            dis[node] = rsqrtf(1.0f + (float)v);   // +1 self-loop
        }
    }
    if (b == 0 && tid == 0) rp[N] = E;
    __syncthreads();

    for (int e = bb + tid; e < be; e += 1024) {
        int ev = ebuf[e];
        int slot = atomicAdd(&cur[ev >> 17], 1);
        esrc[bb + slot] = ev & SMASK;
    }
}

// ---- 3-step exclusive scan (for the [bucket][block] matrix) ----
#define SCAN_B 1024
__global__ void k_scan1(const int* __restrict__ cnt, int* __restrict__ rp,
                        int* __restrict__ bsum, int n) {
    __shared__ int sm[SCAN_B];
    const int tid = threadIdx.x;
    const int gid = blockIdx.x * SCAN_B + tid;
    int v = (gid < n) ? cnt[gid] : 0;
    sm[tid] = v;
    __syncthreads();
    for (int off = 1; off < SCAN_B; off <<= 1) {
        int t = (tid >= off) ? sm[tid - off] : 0;
        __syncthreads();
        sm[tid] += t;
        __syncthreads();
    }
    if (gid < n) rp[gid] = sm[tid] - v;           // exclusive
    if (tid == SCAN_B - 1) bsum[blockIdx.x] = sm[tid];
}

__global__ void k_scan2(int* __restrict__ bsum, int nb) {
    __shared__ int sm[SCAN_B];
    const int tid = threadIdx.x;
    int v = (tid < nb) ? bsum[tid] : 0;
    sm[tid] = v;
    __syncthreads();
    for (int off = 1; off < SCAN_B; off <<= 1) {
        int t = (tid >= off) ? sm[tid - off] : 0;
        __syncthreads();
        sm[tid] += t;
        __syncthreads();
    }
    if (tid < nb) bsum[tid] = sm[tid] - v;        // exclusive
}

__global__ void k_scan3(int* __restrict__ rp, const int* __restrict__ bsum, int n, int E) {
    const int gid = blockIdx.x * SCAN_B + threadIdx.x;
    if (gid < n) rp[gid] += bsum[gid / SCAN_B];
    if (gid == n) rp[n] = E;
}

__device__ __forceinline__ void fma4(float a, const float4& w, float4& acc) {
    acc.x = fmaf(a, w.x, acc.x);
    acc.y = fmaf(a, w.y, acc.y);
    acc.z = fmaf(a, w.z, acc.z);
    acc.w = fmaf(a, w.w, acc.w);
}

// LDS-tiled GEMM with fused dis-scale: Hs[N,64] = (X[N,K] @ W[K,64]) * dis[row].
template<int K, bool BF16OUT>
__global__ __launch_bounds__(256, 2)
void k_gemm_lds(const float* __restrict__ X, const float* __restrict__ W,
                const float* __restrict__ dis, void* __restrict__ Hout, int N) {
    constexpr int KP = K + 4;                 // padded X row stride (floats)
    __shared__ float xs[64 * KP];
    __shared__ float wsh[K * 64];
    const int tid = threadIdx.x;
    const int tx = tid & 15;                  // col group (4 cols)
    const int ty = tid >> 4;                  // row group (4 rows)
    const int row0 = blockIdx.x * 64;

    {
        const float4* Wg = (const float4*)W;
        float4* Wl = (float4*)wsh;
#pragma unroll
        for (int i = 0; i < K * 16 / 256; ++i)
            Wl[i * 256 + tid] = Wg[i * 256 + tid];
    }
    {
        constexpr int F4 = K / 4;             // float4 per row
        for (int i = tid; i < 64 * F4; i += 256) {
            int r = i / F4, c = i - r * F4;
            int gr = min(row0 + r, N - 1);
            float4 v = *(const float4*)(X + (size_t)gr * K + c * 4);
            *(float4*)(xs + r * KP + c * 4) = v;
        }
    }
    __syncthreads();

    float4 acc0 = {0.f, 0.f, 0.f, 0.f};
    float4 acc1 = {0.f, 0.f, 0.f, 0.f};
    float4 acc2 = {0.f, 0.f, 0.f, 0.f};
    float4 acc3 = {0.f, 0.f, 0.f, 0.f};

    const float* xr0 = xs + (ty * 4 + 0) * KP;
    const float* xr1 = xs + (ty * 4 + 1) * KP;
    const float* xr2 = xs + (ty * 4 + 2) * KP;
    const float* xr3 = xs + (ty * 4 + 3) * KP;

#pragma unroll 2
    for (int k = 0; k < K; k += 4) {
        float4 w0 = *(const float4*)(wsh + (k + 0) * 64 + tx * 4);
        float4 w1 = *(const float4*)(wsh + (k + 1) * 64 + tx * 4);
        float4 w2 = *(const float4*)(wsh + (k + 2) * 64 + tx * 4);
        float4 w3 = *(const float4*)(wsh + (k + 3) * 64 + tx * 4);
        float4 xa = *(const float4*)(xr0 + k);
        float4 xb = *(const float4*)(xr1 + k);
        float4 xc = *(const float4*)(xr2 + k);
        float4 xd = *(const float4*)(xr3 + k);

        fma4(xa.x, w0, acc0); fma4(xa.y, w1, acc0); fma4(xa.z, w2, acc0); fma4(xa.w, w3, acc0);
        fma4(xb.x, w0, acc1); fma4(xb.y, w1, acc1); fma4(xb.z, w2, acc1); fma4(xb.w, w3, acc1);
        fma4(xc.x, w0, acc2); fma4(xc.y, w1, acc2); fma4(xc.z, w2, acc2); fma4(xc.w, w3, acc2);
        fma4(xd.x, w0, acc3); fma4(xd.y, w1, acc3); fma4(xd.z, w2, acc3); fma4(xd.w, w3, acc3);
    }

    const int r = row0 + ty * 4;
#pragma unroll
    for (int i = 0; i < 4; ++i) {
        if (r + i >= N) break;
        float4 a = (i == 0) ? acc0 : (i == 1) ? acc1 : (i == 2) ? acc2 : acc3;
        float d = dis[r + i];
        a.x *= d; a.y *= d; a.z *= d; a.w *= d;
        if (BF16OUT) {
            ushort4 o;
            o.x = f2bf(a.x); o.y = f2bf(a.y); o.z = f2bf(a.z); o.w = f2bf(a.w);
            *(ushort4*)((unsigned short*)Hout + (size_t)(r + i) * 64 + tx * 4) = o;
        } else {
            *(float4*)((float*)Hout + (size_t)(r + i) * 64 + tx * 4) = a;
        }
    }
}

// Wave-per-node segmented row-sum, quad-per-edge, bf16 gather rows (128 B).
// R1 structure verbatim (measured 44.8 us, at the gather floor). No LDS,
// no barrier, waves fully independent.
// MODE 0: A = relu(t + bias)           -> fp32  (layer 1, GEMM input)
// MODE 1: A = relu(t + bias) * dis[d]  -> bf16  (a2s, zgemm input)
template<int MODE>
__global__ __launch_bounds__(256, 8)
void k_agg(const unsigned short* __restrict__ Hs, const float* __restrict__ dis,
           const int* __restrict__ rp, const int* __restrict__ esrc,
           const float* __restrict__ bias, void* __restrict__ A, int N) {
    const int wave = threadIdx.x >> 6;
    const int lane = threadIdx.x & 63;
    const int node = blockIdx.x * (blockDim.x >> 6) + wave;
    if (node >= N) return;
    const int q  = lane >> 4;          // quad 0..3 -> interleaved edges
    const int f4 = lane & 15;          // 4-feature group within the 64-f row

    const int e0 = rp[node];
    const int e1 = rp[node + 1];
    float4 acc = {0.f, 0.f, 0.f, 0.f};
    int e = e0 + q;
    for (; e + 4 < e1; e += 8) {       // 2 edges per quad per round
        int s0 = esrc[e];
        int s1 = esrc[e + 4];
        ushort4 h0 = *(const ushort4*)(Hs + (size_t)s0 * 64 + f4 * 4);
        ushort4 h1 = *(const ushort4*)(Hs + (size_t)s1 * 64 + f4 * 4);
        acc.x += bf2f(h0.x) + bf2f(h1.x);
        acc.y += bf2f(h0.y) + bf2f(h1.y);
        acc.z += bf2f(h0.z) + bf2f(h1.z);
        acc.w += bf2f(h0.w) + bf2f(h1.w);
    }
    for (; e < e1; e += 4) {
        int s = esrc[e];
        ushort4 h = *(const ushort4*)(Hs + (size_t)s * 64 + f4 * 4);
        acc.x += bf2f(h.x); acc.y += bf2f(h.y); acc.z += bf2f(h.z); acc.w += bf2f(h.w);
    }
    // cross-quad reduce (after: lanes 0..15 hold the full row sum)
    acc.x += __shfl_xor(acc.x, 16, 64);
    acc.y += __shfl_xor(acc.y, 16, 64);
    acc.z += __shfl_xor(acc.z, 16, 64);
    acc.w += __shfl_xor(acc.w, 16, 64);
    acc.x += __shfl_xor(acc.x, 32, 64);
    acc.y += __shfl_xor(acc.y, 32, 64);
    acc.z += __shfl_xor(acc.z, 32, 64);
    acc.w += __shfl_xor(acc.w, 32, 64);

    if (lane < 16) {
        const float dd = dis[node];
        ushort4 sh = *(const ushort4*)(Hs + (size_t)node * 64 + lane * 4);
        float4 v;
        v.x = (acc.x + bf2f(sh.x)) * dd;
        v.y = (acc.y + bf2f(sh.y)) * dd;
        v.z = (acc.z + bf2f(sh.z)) * dd;
        v.w = (acc.w + bf2f(sh.w)) * dd;
        float4 bv = ((const float4*)bias)[lane];
        v.x = fmaxf(v.x + bv.x, 0.f);
        v.y = fmaxf(v.y + bv.y, 0.f);
        v.z = fmaxf(v.z + bv.z, 0.f);
        v.w = fmaxf(v.w + bv.w, 0.f);
        if (MODE == 1) {
            v.x *= dd; v.y *= dd; v.z *= dd; v.w *= dd;
            ushort4 o;
            o.x = f2bf(v.x); o.y = f2bf(v.y); o.z = f2bf(v.z); o.w = f2bf(v.w);
            *(ushort4*)((unsigned short*)A + (size_t)node * 64 + lane * 4) = o;
        } else {
            *(float4*)((float*)A + (size_t)node * 64 + lane * 4) = v;
        }
    }
}

// z64[n, 0..39] = bf16(a2s[n,:64] @ W3), row stride 64 (128 B, pad ignored).
// Lane c holds W3[:,c]; a2s row via wave-uniform uint4 loads + shift-unpack.
__global__ __launch_bounds__(256, 4)
void k_zgemm(const unsigned short* __restrict__ A2s, const float* __restrict__ W,
             unsigned short* __restrict__ Z, int N, int npw) {
    const int wid  = blockIdx.x * (blockDim.x >> 6) + (threadIdx.x >> 6);
    const int lane = threadIdx.x & 63;
    const int cl   = (lane < 40) ? lane : 0;

    float w[64];
#pragma unroll
    for (int k = 0; k < 64; ++k) w[k] = W[k * 40 + cl];

    const int n0 = wid * npw;
    const int n1 = min(n0 + npw, N);
    for (int node = n0; node < n1; ++node) {
        const int un = __builtin_amdgcn_readfirstlane(node);
        const uint4* xr = (const uint4*)(A2s + (size_t)un * 64);
        float acc = 0.0f;
#pragma unroll
        for (int j = 0; j < 8; ++j) {
            uint4 u = xr[j];
            acc = fmaf(__uint_as_float(u.x << 16),          w[8 * j + 0], acc);
            acc = fmaf(__uint_as_float(u.x & 0xffff0000u),  w[8 * j + 1], acc);
            acc = fmaf(__uint_as_float(u.y << 16),          w[8 * j + 2], acc);
            acc = fmaf(__uint_as_float(u.y & 0xffff0000u),  w[8 * j + 3], acc);
            acc = fmaf(__uint_as_float(u.z << 16),          w[8 * j + 4], acc);
            acc = fmaf(__uint_as_float(u.z & 0xffff0000u),  w[8 * j + 5], acc);
            acc = fmaf(__uint_as_float(u.w << 16),          w[8 * j + 6], acc);
            acc = fmaf(__uint_as_float(u.w & 0xffff0000u),  w[8 * j + 7], acc);
        }
        if (lane < 40) Z[(size_t)node * 64 + lane] = f2bf(acc);
    }
}

// Layer-3 gather + log_softmax, k_agg geometry on the z64 table:
// 4 quads x 16 lanes x ushort4 over 128 B rows (features 40..63 are junk,
// masked in the epilogue). Wave-local shfl-only lsm: no LDS, no barrier.
__global__ __launch_bounds__(256, 8)
void k_aggz(const unsigned short* __restrict__ Z, const float* __restrict__ dis,
            const int* __restrict__ rp, const int* __restrict__ esrc,
            const float* __restrict__ b3, float* __restrict__ out, int N) {
    const int wave = threadIdx.x >> 6;
    const int lane = threadIdx.x & 63;
    const int node = blockIdx.x * (blockDim.x >> 6) + wave;
    if (node >= N) return;
    const int q  = lane >> 4;
    const int f4 = lane & 15;

    const int e0 = rp[node];
    const int e1 = rp[node + 1];
    float4 acc = {0.f, 0.f, 0.f, 0.f};
    int e = e0 + q;
    for (; e + 4 < e1; e += 8) {
        int s0 = esrc[e];
        int s1 = esrc[e + 4];
        ushort4 h0 = *(const ushort4*)(Z + (size_t)s0 * 64 + f4 * 4);
        ushort4 h1 = *(const ushort4*)(Z + (size_t)s1 * 64 + f4 * 4);
        acc.x += bf2f(h0.x) + bf2f(h1.x);
        acc.y += bf2f(h0.y) + bf2f(h1.y);
        acc.z += bf2f(h0.z) + bf2f(h1.z);
        acc.w += bf2f(h0.w) + bf2f(h1.w);
    }
    for (; e < e1; e += 4) {
        int s = esrc[e];
        ushort4 h = *(const ushort4*)(Z + (size_t)s * 64 + f4 * 4);
        acc.x += bf2f(h.x); acc.y += bf2f(h.y); acc.z += bf2f(h.z); acc.w += bf2f(h.w);
    }
    // cross-quad reduce: all lanes end with the full 4-feature sums for f4
    acc.x += __shfl_xor(acc.x, 16, 64);
    acc.y += __shfl_xor(acc.y, 16, 64);
    acc.z += __shfl_xor(acc.z, 16, 64);
    acc.w += __shfl_xor(acc.w, 16, 64);
    acc.x += __shfl_xor(acc.x, 32, 64);
    acc.y += __shfl_xor(acc.y, 32, 64);
    acc.z += __shfl_xor(acc.z, 32, 64);
    acc.w += __shfl_xor(acc.w, 32, 64);

    // wave-local log-softmax over features 0..39 (f4 < 10)
    const float dd = dis[node];
    ushort4 sh = *(const ushort4*)(Z + (size_t)node * 64 + f4 * 4);
    float4 bv = {0.f, 0.f, 0.f, 0.f};
    if (f4 < 10) bv = ((const float4*)b3)[f4];
    float4 v;
    v.x = (acc.x + bf2f(sh.x)) * dd + bv.x;
    v.y = (acc.y + bf2f(sh.y)) * dd + bv.y;
    v.z = (acc.z + bf2f(sh.z)) * dd + bv.z;
    v.w = (acc.w + bf2f(sh.w)) * dd + bv.w;

    float m = (f4 < 10) ? fmaxf(fmaxf(v.x, v.y), fmaxf(v.z, v.w)) : -INFINITY;
#pragma unroll
    for (int o = 1; o < 16; o <<= 1) m = fmaxf(m, __shfl_xor(m, o, 64));
    float es = (f4 < 10)
        ? expf(v.x - m) + expf(v.y - m) + expf(v.z - m) + expf(v.w - m) : 0.f;
#pragma unroll
    for (int o = 1; o < 16; o <<= 1) es += __shfl_xor(es, o, 64);

    if (lane < 10) {                   // q==0 && f4<10
        float ls = logf(es);
        float4 o4;
        o4.x = v.x - m - ls;
        o4.y = v.y - m - ls;
        o4.z = v.z - m - ls;
        o4.w = v.w - m - ls;
        *(float4*)(out + (size_t)node * 40 + lane * 4) = o4;
    }
}

extern "C" void kernel_launch(void* const* d_in, const int* in_sizes, int n_in,
                              void* d_out, int out_size, void* d_ws, size_t ws_size,
                              hipStream_t stream) {
    const float* x  = (const float*)d_in[0];
    const int*   ei = (const int*)d_in[1];
    const float* W1 = (const float*)d_in[2];
    const float* b1 = (const float*)d_in[3];
    const float* W2 = (const float*)d_in[4];
    const float* b2 = (const float*)d_in[5];
    const float* W3 = (const float*)d_in[6];
    const float* b3 = (const float*)d_in[7];
    float* out = (float*)d_out;

    const int N = in_sizes[0] / 128;
    const int E = in_sizes[1] / 2;
    const int* src = ei;
    const int* dst = ei + E;

    const int NB   = cdiv(N, RNODES);        // buckets (196 @ N=100000)
    const int EPB  = cdiv(E, GB);            // edges per hist/scatter block
    const int nscan = NB * GB;               // scan length (50176)

    // ---- workspace layout ----
    // buf0: ebuf int (CSR build) -> Hs1 bf16 -> Hs2 bf16 -> z64 bf16
    // buf1: a1 fp32 -> a2s bf16
    char* ws = (char*)d_ws;
    char* buf0  = ws;                         ws += (size_t)N * 64 * sizeof(float); // 25.6 MB
    char* buf1  = ws;                         ws += (size_t)N * 64 * sizeof(float); // 25.6 MB
    int*   esrc  = (int*)ws;                  ws += (size_t)E * sizeof(int);        // 4.8 MB
    int*   rp    = (int*)ws;                  ws += (size_t)(N + 1) * sizeof(int);
    int*   bsum  = (int*)ws;                  ws += (size_t)SCAN_B * sizeof(int);
    float* dis   = (float*)ws;                ws += (size_t)N * sizeof(float);
    int*   bh    = (int*)ws;                  ws += (size_t)nscan * sizeof(int);    // 200 KB
    int*   eoff  = (int*)ws;                  ws += (size_t)(nscan + 1) * sizeof(int);
    int*   ebuf  = (int*)buf0;                // 4.8 MB, consumed before gemm1 writes buf0

    const int B = 256;
    const int nbs = cdiv(nscan, SCAN_B);

    // ---- CSR build: two-level counting sort, zero global atomics ----
    k_bhist<<<GB, B, 0, stream>>>(dst, bh, E, NB, EPB);
    k_scan1<<<nbs, SCAN_B, 0, stream>>>(bh, eoff, bsum, nscan);
    k_scan2<<<1, SCAN_B, 0, stream>>>(bsum, nbs);
    k_scan3<<<cdiv(nscan + 1, SCAN_B), SCAN_B, 0, stream>>>(eoff, bsum, nscan, E);
    k_bscatter<<<GB, B, 0, stream>>>(src, dst, eoff, ebuf, E, NB, EPB);
    k_csr<<<NB, 1024, 0, stream>>>(ebuf, eoff, rp, dis, esrc, N, E, NB);

    // ---- layer 1: Hs1 = bf16((x@W1)*dis); a1 = relu(dis*sum + b1) fp32 ----
    k_gemm_lds<128, true><<<cdiv(N, 64), B, 0, stream>>>(x, W1, dis, buf0, N);
    k_agg<0><<<cdiv(N, 4), B, 0, stream>>>((const unsigned short*)buf0, dis, rp, esrc,
                                           b1, buf1, N);

    // ---- layer 2: Hs2 = bf16((a1@W2)*dis); a2s = bf16(relu(dis*sum+b2)*dis) ----
    k_gemm_lds<64, true><<<cdiv(N, 64), B, 0, stream>>>((const float*)buf1, W2, dis, buf0, N);
    k_agg<1><<<cdiv(N, 4), B, 0, stream>>>((const unsigned short*)buf0, dis, rp, esrc,
                                           b2, buf1, N);

    // ---- layer 3: z64 = a2s @ W3 (stride-64 rows); out = lsm gather ----
    const int NW = 8192;                      // 2048 blocks x 4 waves
    const int npw = cdiv(N, NW);
    k_zgemm<<<NW / 4, B, 0, stream>>>((const unsigned short*)buf1, W3,
                                      (unsigned short*)buf0, N, npw);
    k_aggz<<<cdiv(N, 4), B, 0, stream>>>((const unsigned short*)buf0, dis, rp, esrc,
                                         b3, out, N);
}

// Round 7
// 322.016 us; speedup vs baseline: 1.1043x; 1.0526x over previous
//
#include <hip/hip_runtime.h>
#include <math.h>

// ---------------------------------------------------------------------------
// 3-layer GCN, CSR-gather formulation.
// Round 20: MLP test done right + occupancy fixes.
//   - 4-deep gated gather (clamped idx + fmaf gates, branchless, no tail):
//     16 row-loads in flight/wave vs 8. Tests latency-vs-service theory
//     cleanly (R17's failed "MLP boost" was confounded by shfl serialization).
//   - a1 stored bf16 (agg<0> bf16 out; gemm64 stages bf16->f32): -12.8MB RT.
//   - gemm64 launch_bounds(256,4): 33.8KB LDS -> 4 blocks/CU.
//   - GB 256->1024: bhist/bscatter 1->4 blocks/CU (random scatter is
//     latency-bound too).
// N=100000, E=1200000, F: 128 -> 64 -> 64 -> 40
// ---------------------------------------------------------------------------

static inline int cdiv(long a, int b) { return (int)((a + b - 1) / b); }

// ---- bf16 helpers (RNE) ----
__device__ __forceinline__ unsigned short f2bf(float f) {
    unsigned u = __float_as_uint(f);
    u += 0x7fffu + ((u >> 16) & 1u);
    return (unsigned short)(u >> 16);
}
__device__ __forceinline__ float bf2f(unsigned short b) {
    return __uint_as_float(((unsigned)b) << 16);
}

// ---- radix-bucket CSR build ----
#define RSH 9
#define RNODES 512            // 1 << RSH nodes per bucket
#define GB 1024               // blocks in bucket-hist / bucket-scatter passes
#define NBMAX 256             // max buckets (N <= 131072)
#define SMASK 0x1FFFF         // 17-bit src mask (N <= 131072)

// K1: per-block bucket histogram (LDS atomics only).
__global__ __launch_bounds__(256)
void k_bhist(const int* __restrict__ dst, int* __restrict__ bh,
             int E, int NB, int EPB) {
    __shared__ int bcnt[NBMAX];
    const int tid = threadIdx.x, blk = blockIdx.x;
    for (int i = tid; i < NB; i += 256) bcnt[i] = 0;
    __syncthreads();
    const int e1 = min(E, (blk + 1) * EPB);
    for (int e = blk * EPB + tid; e < e1; e += 256)
        atomicAdd(&bcnt[dst[e] >> RSH], 1);
    __syncthreads();
    for (int i = tid; i < NB; i += 256) bh[i * GB + blk] = bcnt[i];
}

// K2: scatter edges into bucket-grouped ebuf (LDS cursors, no global atomics).
// Packed entry: (dst & 511) << 17 | src.
__global__ __launch_bounds__(256)
void k_bscatter(const int* __restrict__ src, const int* __restrict__ dst,
                const int* __restrict__ eoff, int* __restrict__ ebuf,
                int E, int NB, int EPB) {
    __shared__ int cur[NBMAX];
    const int tid = threadIdx.x, blk = blockIdx.x;
    for (int i = tid; i < NB; i += 256) cur[i] = eoff[i * GB + blk];
    __syncthreads();
    const int e1 = min(E, (blk + 1) * EPB);
    for (int e = blk * EPB + tid; e < e1; e += 256) {
        int d = dst[e];
        int s = src[e];
        int pos = atomicAdd(&cur[d >> RSH], 1);
        ebuf[pos] = ((d & (RNODES - 1)) << 17) | s;
    }
}

// K3: per-bucket CSR finalize (LDS hist + scan + rank-scatter).
__global__ __launch_bounds__(1024)
void k_csr(const int* __restrict__ ebuf, const int* __restrict__ eoff,
           int* __restrict__ rp, float* __restrict__ dis, int* __restrict__ esrc,
           int N, int E, int NB) {
    __shared__ int cnt[RNODES];
    __shared__ int cur[RNODES];
    __shared__ int sm[1024];
    const int tid = threadIdx.x, b = blockIdx.x;
    const int node0 = b << RSH;
    const int bb = eoff[b * GB];
    const int be = (b + 1 == NB) ? E : eoff[(b + 1) * GB];

    if (tid < RNODES) cnt[tid] = 0;
    __syncthreads();
    for (int e = bb + tid; e < be; e += 1024)
        atomicAdd(&cnt[ebuf[e] >> 17], 1);
    __syncthreads();

    int v = (tid < RNODES) ? cnt[tid] : 0;
    sm[tid] = v;
    __syncthreads();
    for (int off = 1; off < RNODES; off <<= 1) {
        int t = (tid >= off) ? sm[tid - off] : 0;
        __syncthreads();
        sm[tid] += t;
        __syncthreads();
    }
    if (tid < RNODES) {
        int excl = sm[tid] - v;
        cur[tid] = excl;
        int node = node0 + tid;
        if (node < N) {
            rp[node] = bb + excl;
            dis[node] = rsqrtf(1.0f + (float)v);   // +1 self-loop
        }
    }
    if (b == 0 && tid == 0) rp[N] = E;
    __syncthreads();

    for (int e = bb + tid; e < be; e += 1024) {
        int ev = ebuf[e];
        int slot = atomicAdd(&cur[ev >> 17], 1);
        esrc[bb + slot] = ev & SMASK;
    }
}

// ---- 3-step exclusive scan (for the [bucket][block] matrix) ----
#define SCAN_B 1024
__global__ void k_scan1(const int* __restrict__ cnt, int* __restrict__ rp,
                        int* __restrict__ bsum, int n) {
    __shared__ int sm[SCAN_B];
    const int tid = threadIdx.x;
    const int gid = blockIdx.x * SCAN_B + tid;
    int v = (gid < n) ? cnt[gid] : 0;
    sm[tid] = v;
    __syncthreads();
    for (int off = 1; off < SCAN_B; off <<= 1) {
        int t = (tid >= off) ? sm[tid - off] : 0;
        __syncthreads();
        sm[tid] += t;
        __syncthreads();
    }
    if (gid < n) rp[gid] = sm[tid] - v;           // exclusive
    if (tid == SCAN_B - 1) bsum[blockIdx.x] = sm[tid];
}

__global__ void k_scan2(int* __restrict__ bsum, int nb) {
    __shared__ int sm[SCAN_B];
    const int tid = threadIdx.x;
    int v = (tid < nb) ? bsum[tid] : 0;
    sm[tid] = v;
    __syncthreads();
    for (int off = 1; off < SCAN_B; off <<= 1) {
        int t = (tid >= off) ? sm[tid - off] : 0;
        __syncthreads();
        sm[tid] += t;
        __syncthreads();
    }
    if (tid < nb) bsum[tid] = sm[tid] - v;        // exclusive
}

__global__ void k_scan3(int* __restrict__ rp, const int* __restrict__ bsum, int n, int E) {
    const int gid = blockIdx.x * SCAN_B + threadIdx.x;
    if (gid < n) rp[gid] += bsum[gid / SCAN_B];
    if (gid == n) rp[n] = E;
}

__device__ __forceinline__ void fma4(float a, const float4& w, float4& acc) {
    acc.x = fmaf(a, w.x, acc.x);
    acc.y = fmaf(a, w.y, acc.y);
    acc.z = fmaf(a, w.z, acc.z);
    acc.w = fmaf(a, w.w, acc.w);
}

// LDS-tiled GEMM with fused dis-scale: Hs[N,64] = (X[N,K] @ W[K,64]) * dis[row].
// BF16IN: X rows are bf16 (stage converts to f32 in LDS; math unchanged).
template<int K, bool BF16IN, int MINW>
__global__ __launch_bounds__(256, MINW)
void k_gemm_lds(const void* __restrict__ Xv, const float* __restrict__ W,
                const float* __restrict__ dis, void* __restrict__ Hout, int N) {
    constexpr int KP = K + 4;                 // padded X row stride (floats)
    __shared__ float xs[64 * KP];
    __shared__ float wsh[K * 64];
    const int tid = threadIdx.x;
    const int tx = tid & 15;                  // col group (4 cols)
    const int ty = tid >> 4;                  // row group (4 rows)
    const int row0 = blockIdx.x * 64;

    {
        const float4* Wg = (const float4*)W;
        float4* Wl = (float4*)wsh;
#pragma unroll
        for (int i = 0; i < K * 16 / 256; ++i)
            Wl[i * 256 + tid] = Wg[i * 256 + tid];
    }
    {
        constexpr int F4 = K / 4;             // 4-elem groups per row
        for (int i = tid; i < 64 * F4; i += 256) {
            int r = i / F4, c = i - r * F4;
            int gr = min(row0 + r, N - 1);
            float4 v;
            if (BF16IN) {
                ushort4 u = *(const ushort4*)((const unsigned short*)Xv + (size_t)gr * K + c * 4);
                v.x = bf2f(u.x); v.y = bf2f(u.y); v.z = bf2f(u.z); v.w = bf2f(u.w);
            } else {
                v = *(const float4*)((const float*)Xv + (size_t)gr * K + c * 4);
            }
            *(float4*)(xs + r * KP + c * 4) = v;
        }
    }
    __syncthreads();

    float4 acc0 = {0.f, 0.f, 0.f, 0.f};
    float4 acc1 = {0.f, 0.f, 0.f, 0.f};
    float4 acc2 = {0.f, 0.f, 0.f, 0.f};
    float4 acc3 = {0.f, 0.f, 0.f, 0.f};

    const float* xr0 = xs + (ty * 4 + 0) * KP;
    const float* xr1 = xs + (ty * 4 + 1) * KP;
    const float* xr2 = xs + (ty * 4 + 2) * KP;
    const float* xr3 = xs + (ty * 4 + 3) * KP;

#pragma unroll 2
    for (int k = 0; k < K; k += 4) {
        float4 w0 = *(const float4*)(wsh + (k + 0) * 64 + tx * 4);
        float4 w1 = *(const float4*)(wsh + (k + 1) * 64 + tx * 4);
        float4 w2 = *(const float4*)(wsh + (k + 2) * 64 + tx * 4);
        float4 w3 = *(const float4*)(wsh + (k + 3) * 64 + tx * 4);
        float4 xa = *(const float4*)(xr0 + k);
        float4 xb = *(const float4*)(xr1 + k);
        float4 xc = *(const float4*)(xr2 + k);
        float4 xd = *(const float4*)(xr3 + k);

        fma4(xa.x, w0, acc0); fma4(xa.y, w1, acc0); fma4(xa.z, w2, acc0); fma4(xa.w, w3, acc0);
        fma4(xb.x, w0, acc1); fma4(xb.y, w1, acc1); fma4(xb.z, w2, acc1); fma4(xb.w, w3, acc1);
        fma4(xc.x, w0, acc2); fma4(xc.y, w1, acc2); fma4(xc.z, w2, acc2); fma4(xc.w, w3, acc2);
        fma4(xd.x, w0, acc3); fma4(xd.y, w1, acc3); fma4(xd.z, w2, acc3); fma4(xd.w, w3, acc3);
    }

    const int r = row0 + ty * 4;
#pragma unroll
    for (int i = 0; i < 4; ++i) {
        if (r + i >= N) break;
        float4 a = (i == 0) ? acc0 : (i == 1) ? acc1 : (i == 2) ? acc2 : acc3;
        float d = dis[r + i];
        a.x *= d; a.y *= d; a.z *= d; a.w *= d;
        ushort4 o;
        o.x = f2bf(a.x); o.y = f2bf(a.y); o.z = f2bf(a.z); o.w = f2bf(a.w);
        *(ushort4*)((unsigned short*)Hout + (size_t)(r + i) * 64 + tx * 4) = o;
    }
}

// Wave-per-node segmented row-sum, quad-per-edge, bf16 gather rows (128 B).
// 4-deep gated gather: clamped indices (always in-bounds) + fmaf gates
// (exact no-op when gate 0). 16 row-loads in flight per wave.
// MODE 0: A = relu(t + bias)           -> bf16  (a1, gemm64 input)
// MODE 1: A = relu(t + bias) * dis[d]  -> bf16  (a2s, zgemm input)
template<int MODE>
__global__ __launch_bounds__(256, 8)
void k_agg(const unsigned short* __restrict__ Hs, const float* __restrict__ dis,
           const int* __restrict__ rp, const int* __restrict__ esrc,
           const float* __restrict__ bias, void* __restrict__ A, int N) {
    const int wave = threadIdx.x >> 6;
    const int lane = threadIdx.x & 63;
    const int node = blockIdx.x * (blockDim.x >> 6) + wave;
    if (node >= N) return;
    const int q  = lane >> 4;          // quad 0..3 -> interleaved edges
    const int f4 = lane & 15;          // 4-feature group within the 64-f row

    const int e0 = rp[node];
    const int e1 = rp[node + 1];
    float4 acc = {0.f, 0.f, 0.f, 0.f};
    for (int e = e0 + q; e < e1; e += 16) {
        const int i1 = min(e + 4,  e1 - 1);
        const int i2 = min(e + 8,  e1 - 1);
        const int i3 = min(e + 12, e1 - 1);
        const float g1 = (e + 4  < e1) ? 1.f : 0.f;
        const float g2 = (e + 8  < e1) ? 1.f : 0.f;
        const float g3 = (e + 12 < e1) ? 1.f : 0.f;
        int s0 = esrc[e];
        int s1 = esrc[i1];
        int s2 = esrc[i2];
        int s3 = esrc[i3];
        ushort4 h0 = *(const ushort4*)(Hs + (size_t)s0 * 64 + f4 * 4);
        ushort4 h1 = *(const ushort4*)(Hs + (size_t)s1 * 64 + f4 * 4);
        ushort4 h2 = *(const ushort4*)(Hs + (size_t)s2 * 64 + f4 * 4);
        ushort4 h3 = *(const ushort4*)(Hs + (size_t)s3 * 64 + f4 * 4);
        acc.x += bf2f(h0.x);
        acc.y += bf2f(h0.y);
        acc.z += bf2f(h0.z);
        acc.w += bf2f(h0.w);
        acc.x = fmaf(g1, bf2f(h1.x), acc.x);
        acc.y = fmaf(g1, bf2f(h1.y), acc.y);
        acc.z = fmaf(g1, bf2f(h1.z), acc.z);
        acc.w = fmaf(g1, bf2f(h1.w), acc.w);
        acc.x = fmaf(g2, bf2f(h2.x), acc.x);
        acc.y = fmaf(g2, bf2f(h2.y), acc.y);
        acc.z = fmaf(g2, bf2f(h2.z), acc.z);
        acc.w = fmaf(g2, bf2f(h2.w), acc.w);
        acc.x = fmaf(g3, bf2f(h3.x), acc.x);
        acc.y = fmaf(g3, bf2f(h3.y), acc.y);
        acc.z = fmaf(g3, bf2f(h3.z), acc.z);
        acc.w = fmaf(g3, bf2f(h3.w), acc.w);
    }
    // cross-quad reduce (after: lanes 0..15 hold the full row sum)
    acc.x += __shfl_xor(acc.x, 16, 64);
    acc.y += __shfl_xor(acc.y, 16, 64);
    acc.z += __shfl_xor(acc.z, 16, 64);
    acc.w += __shfl_xor(acc.w, 16, 64);
    acc.x += __shfl_xor(acc.x, 32, 64);
    acc.y += __shfl_xor(acc.y, 32, 64);
    acc.z += __shfl_xor(acc.z, 32, 64);
    acc.w += __shfl_xor(acc.w, 32, 64);

    if (lane < 16) {
        const float dd = dis[node];
        ushort4 sh = *(const ushort4*)(Hs + (size_t)node * 64 + lane * 4);
        float4 v;
        v.x = (acc.x + bf2f(sh.x)) * dd;
        v.y = (acc.y + bf2f(sh.y)) * dd;
        v.z = (acc.z + bf2f(sh.z)) * dd;
        v.w = (acc.w + bf2f(sh.w)) * dd;
        float4 bv = ((const float4*)bias)[lane];
        v.x = fmaxf(v.x + bv.x, 0.f);
        v.y = fmaxf(v.y + bv.y, 0.f);
        v.z = fmaxf(v.z + bv.z, 0.f);
        v.w = fmaxf(v.w + bv.w, 0.f);
        if (MODE == 1) {
            v.x *= dd; v.y *= dd; v.z *= dd; v.w *= dd;
        }
        ushort4 o;
        o.x = f2bf(v.x); o.y = f2bf(v.y); o.z = f2bf(v.z); o.w = f2bf(v.w);
        *(ushort4*)((unsigned short*)A + (size_t)node * 64 + lane * 4) = o;
    }
}

// z64[n, 0..39] = bf16(a2s[n,:64] @ W3), row stride 64 (128 B, pad ignored).
__global__ __launch_bounds__(256, 4)
void k_zgemm(const unsigned short* __restrict__ A2s, const float* __restrict__ W,
             unsigned short* __restrict__ Z, int N, int npw) {
    const int wid  = blockIdx.x * (blockDim.x >> 6) + (threadIdx.x >> 6);
    const int lane = threadIdx.x & 63;
    const int cl   = (lane < 40) ? lane : 0;

    float w[64];
#pragma unroll
    for (int k = 0; k < 64; ++k) w[k] = W[k * 40 + cl];

    const int n0 = wid * npw;
    const int n1 = min(n0 + npw, N);
    for (int node = n0; node < n1; ++node) {
        const int un = __builtin_amdgcn_readfirstlane(node);
        const uint4* xr = (const uint4*)(A2s + (size_t)un * 64);
        float acc = 0.0f;
#pragma unroll
        for (int j = 0; j < 8; ++j) {
            uint4 u = xr[j];
            acc = fmaf(__uint_as_float(u.x << 16),          w[8 * j + 0], acc);
            acc = fmaf(__uint_as_float(u.x & 0xffff0000u),  w[8 * j + 1], acc);
            acc = fmaf(__uint_as_float(u.y << 16),          w[8 * j + 2], acc);
            acc = fmaf(__uint_as_float(u.y & 0xffff0000u),  w[8 * j + 3], acc);
            acc = fmaf(__uint_as_float(u.z << 16),          w[8 * j + 4], acc);
            acc = fmaf(__uint_as_float(u.z & 0xffff0000u),  w[8 * j + 5], acc);
            acc = fmaf(__uint_as_float(u.w << 16),          w[8 * j + 6], acc);
            acc = fmaf(__uint_as_float(u.w & 0xffff0000u),  w[8 * j + 7], acc);
        }
        if (lane < 40) Z[(size_t)node * 64 + lane] = f2bf(acc);
    }
}

// Layer-3 gather + log_softmax over z64 (128 B rows, 40 valid features).
// Same 4-deep gated gather; wave-local shfl-only lsm epilogue.
__global__ __launch_bounds__(256, 8)
void k_aggz(const unsigned short* __restrict__ Z, const float* __restrict__ dis,
            const int* __restrict__ rp, const int* __restrict__ esrc,
            const float* __restrict__ b3, float* __restrict__ out, int N) {
    const int wave = threadIdx.x >> 6;
    const int lane = threadIdx.x & 63;
    const int node = blockIdx.x * (blockDim.x >> 6) + wave;
    if (node >= N) return;
    const int q  = lane >> 4;
    const int f4 = lane & 15;

    const int e0 = rp[node];
    const int e1 = rp[node + 1];
    float4 acc = {0.f, 0.f, 0.f, 0.f};
    for (int e = e0 + q; e < e1; e += 16) {
        const int i1 = min(e + 4,  e1 - 1);
        const int i2 = min(e + 8,  e1 - 1);
        const int i3 = min(e + 12, e1 - 1);
        const float g1 = (e + 4  < e1) ? 1.f : 0.f;
        const float g2 = (e + 8  < e1) ? 1.f : 0.f;
        const float g3 = (e + 12 < e1) ? 1.f : 0.f;
        int s0 = esrc[e];
        int s1 = esrc[i1];
        int s2 = esrc[i2];
        int s3 = esrc[i3];
        ushort4 h0 = *(const ushort4*)(Z + (size_t)s0 * 64 + f4 * 4);
        ushort4 h1 = *(const ushort4*)(Z + (size_t)s1 * 64 + f4 * 4);
        ushort4 h2 = *(const ushort4*)(Z + (size_t)s2 * 64 + f4 * 4);
        ushort4 h3 = *(const ushort4*)(Z + (size_t)s3 * 64 + f4 * 4);
        acc.x += bf2f(h0.x);
        acc.y += bf2f(h0.y);
        acc.z += bf2f(h0.z);
        acc.w += bf2f(h0.w);
        acc.x = fmaf(g1, bf2f(h1.x), acc.x);
        acc.y = fmaf(g1, bf2f(h1.y), acc.y);
        acc.z = fmaf(g1, bf2f(h1.z), acc.z);
        acc.w = fmaf(g1, bf2f(h1.w), acc.w);
        acc.x = fmaf(g2, bf2f(h2.x), acc.x);
        acc.y = fmaf(g2, bf2f(h2.y), acc.y);
        acc.z = fmaf(g2, bf2f(h2.z), acc.z);
        acc.w = fmaf(g2, bf2f(h2.w), acc.w);
        acc.x = fmaf(g3, bf2f(h3.x), acc.x);
        acc.y = fmaf(g3, bf2f(h3.y), acc.y);
        acc.z = fmaf(g3, bf2f(h3.z), acc.z);
        acc.w = fmaf(g3, bf2f(h3.w), acc.w);
    }
    // cross-quad reduce: all lanes end with the full 4-feature sums for f4
    acc.x += __shfl_xor(acc.x, 16, 64);
    acc.y += __shfl_xor(acc.y, 16, 64);
    acc.z += __shfl_xor(acc.z, 16, 64);
    acc.w += __shfl_xor(acc.w, 16, 64);
    acc.x += __shfl_xor(acc.x, 32, 64);
    acc.y += __shfl_xor(acc.y, 32, 64);
    acc.z += __shfl_xor(acc.z, 32, 64);
    acc.w += __shfl_xor(acc.w, 32, 64);

    // wave-local log-softmax over features 0..39 (f4 < 10)
    const float dd = dis[node];
    ushort4 sh = *(const ushort4*)(Z + (size_t)node * 64 + f4 * 4);
    float4 bv = {0.f, 0.f, 0.f, 0.f};
    if (f4 < 10) bv = ((const float4*)b3)[f4];
    float4 v;
    v.x = (acc.x + bf2f(sh.x)) * dd + bv.x;
    v.y = (acc.y + bf2f(sh.y)) * dd + bv.y;
    v.z = (acc.z + bf2f(sh.z)) * dd + bv.z;
    v.w = (acc.w + bf2f(sh.w)) * dd + bv.w;

    float m = (f4 < 10) ? fmaxf(fmaxf(v.x, v.y), fmaxf(v.z, v.w)) : -INFINITY;
#pragma unroll
    for (int o = 1; o < 16; o <<= 1) m = fmaxf(m, __shfl_xor(m, o, 64));
    float es = (f4 < 10)
        ? expf(v.x - m) + expf(v.y - m) + expf(v.z - m) + expf(v.w - m) : 0.f;
#pragma unroll
    for (int o = 1; o < 16; o <<= 1) es += __shfl_xor(es, o, 64);

    if (lane < 10) {                   // q==0 && f4<10
        float ls = logf(es);
        float4 o4;
        o4.x = v.x - m - ls;
        o4.y = v.y - m - ls;
        o4.z = v.z - m - ls;
        o4.w = v.w - m - ls;
        *(float4*)(out + (size_t)node * 40 + lane * 4) = o4;
    }
}

extern "C" void kernel_launch(void* const* d_in, const int* in_sizes, int n_in,
                              void* d_out, int out_size, void* d_ws, size_t ws_size,
                              hipStream_t stream) {
    const float* x  = (const float*)d_in[0];
    const int*   ei = (const int*)d_in[1];
    const float* W1 = (const float*)d_in[2];
    const float* b1 = (const float*)d_in[3];
    const float* W2 = (const float*)d_in[4];
    const float* b2 = (const float*)d_in[5];
    const float* W3 = (const float*)d_in[6];
    const float* b3 = (const float*)d_in[7];
    float* out = (float*)d_out;

    const int N = in_sizes[0] / 128;
    const int E = in_sizes[1] / 2;
    const int* src = ei;
    const int* dst = ei + E;

    const int NB   = cdiv(N, RNODES);        // buckets (196 @ N=100000)
    const int EPB  = cdiv(E, GB);            // edges per hist/scatter block
    const int nscan = NB * GB;               // scan length (200704)

    // ---- workspace layout ----
    // buf0: ebuf int (CSR build) -> Hs1 bf16 -> Hs2 bf16 -> z64 bf16
    // buf1: a1 bf16 -> a2s bf16
    char* ws = (char*)d_ws;
    char* buf0  = ws;                         ws += (size_t)N * 64 * sizeof(float); // 25.6 MB
    char* buf1  = ws;                         ws += (size_t)N * 64 * sizeof(float); // 25.6 MB
    int*   esrc  = (int*)ws;                  ws += (size_t)E * sizeof(int);        // 4.8 MB
    int*   rp    = (int*)ws;                  ws += (size_t)(N + 1) * sizeof(int);
    int*   bsum  = (int*)ws;                  ws += (size_t)SCAN_B * sizeof(int);
    float* dis   = (float*)ws;                ws += (size_t)N * sizeof(float);
    int*   bh    = (int*)ws;                  ws += (size_t)nscan * sizeof(int);    // 803 KB
    int*   eoff  = (int*)ws;                  ws += (size_t)(nscan + 1) * sizeof(int);
    int*   ebuf  = (int*)buf0;                // 4.8 MB, consumed before gemm1 writes buf0

    const int B = 256;
    const int nbs = cdiv(nscan, SCAN_B);

    // ---- CSR build: two-level counting sort, zero global atomics ----
    k_bhist<<<GB, B, 0, stream>>>(dst, bh, E, NB, EPB);
    k_scan1<<<nbs, SCAN_B, 0, stream>>>(bh, eoff, bsum, nscan);
    k_scan2<<<1, SCAN_B, 0, stream>>>(bsum, nbs);
    k_scan3<<<cdiv(nscan + 1, SCAN_B), SCAN_B, 0, stream>>>(eoff, bsum, nscan, E);
    k_bscatter<<<GB, B, 0, stream>>>(src, dst, eoff, ebuf, E, NB, EPB);
    k_csr<<<NB, 1024, 0, stream>>>(ebuf, eoff, rp, dis, esrc, N, E, NB);

    // ---- layer 1: Hs1 = bf16((x@W1)*dis); a1 = bf16(relu(dis*sum + b1)) ----
    k_gemm_lds<128, false, 2><<<cdiv(N, 64), B, 0, stream>>>(x, W1, dis, buf0, N);
    k_agg<0><<<cdiv(N, 4), B, 0, stream>>>((const unsigned short*)buf0, dis, rp, esrc,
                                           b1, buf1, N);

    // ---- layer 2: Hs2 = bf16((a1@W2)*dis); a2s = bf16(relu(dis*sum+b2)*dis) ----
    k_gemm_lds<64, true, 4><<<cdiv(N, 64), B, 0, stream>>>(buf1, W2, dis, buf0, N);
    k_agg<1><<<cdiv(N, 4), B, 0, stream>>>((const unsigned short*)buf0, dis, rp, esrc,
                                           b2, buf1, N);

    // ---- layer 3: z64 = a2s @ W3 (stride-64 rows); out = lsm gather ----
    const int NW = 8192;                      // 2048 blocks x 4 waves
    const int npw = cdiv(N, NW);
    k_zgemm<<<NW / 4, B, 0, stream>>>((const unsigned short*)buf1, W3,
                                      (unsigned short*)buf0, N, npw);
    k_aggz<<<cdiv(N, 4), B, 0, stream>>>((const unsigned short*)buf0, dis, rp, esrc,
                                         b3, out, N);
}